// Round 14
// baseline (176796.680 us; speedup 1.0000x reference)
//
#include <hip/hip_runtime.h>

// FPS: x (B=64, N=65536, 3) f32 -> out (B, M=2048, 3) f32 gathered points.
// Verified fp semantics (round 3, absmax=0):
//   d = fma(dz,dz, round(dx*dx) + round(dy*dy)), min via fminf,
//   argmax tie-break = smallest global index.
// Round-14: Q=1 — ONE block per batch (64 blocks x 1024 threads, 64 pts
// per thread, all register-resident). The entire global exchange and
// inter-block straggler coupling disappear; iteration = compute ->
// tournament -> wave DPP argmax -> LDS deposit -> bar1 -> wave0 DPP
// combine -> stamped LDS broadcast (r13-proven race-free release chain).

#define FPS_B 64
#define FPS_N 65536
#define FPS_M 2048
#define FPS_T 1024
#define FPS_NP 32                  // v2f point-pairs per thread (64 points)
#define FPS_WAVES (FPS_T / 64)

#define WG_LOAD(p)    __hip_atomic_load((p), __ATOMIC_RELAXED, __HIP_MEMORY_SCOPE_WORKGROUP)
#define WG_STORE(p,v) __hip_atomic_store((p), (v), __ATOMIC_RELAXED, __HIP_MEMORY_SCOPE_WORKGROUP)

typedef float v2f __attribute__((ext_vector_type(2)));

static __device__ __forceinline__ v2f pk_add(v2f a, v2f b) {
    v2f d; asm("v_pk_add_f32 %0, %1, %2" : "=v"(d) : "v"(a), "v"(b)); return d;
}
static __device__ __forceinline__ v2f pk_mul(v2f a, v2f b) {
    v2f d; asm("v_pk_mul_f32 %0, %1, %2" : "=v"(d) : "v"(a), "v"(b)); return d;
}
static __device__ __forceinline__ v2f pk_fma(v2f a, v2f b, v2f c) {
    v2f d; asm("v_pk_fma_f32 %0, %1, %2, %3" : "=v"(d) : "v"(a), "v"(b), "v"(c)); return d;
}

#define PIN4(a,b,c,d) asm volatile("" : "+v"(a), "+v"(b), "+v"(c), "+v"(d))

// 6-step DPP max-reduce for nonneg u32 (identity 0); result in lane 63.
// (verbatim from r13 — proven by absmax=0 across 131K argmaxes)
static __device__ __forceinline__ unsigned dppmax(unsigned x) {
    unsigned y;
    y = (unsigned)__builtin_amdgcn_update_dpp(0, (int)x, 0x111, 0xf, 0xf, true); x = x > y ? x : y;
    y = (unsigned)__builtin_amdgcn_update_dpp(0, (int)x, 0x112, 0xf, 0xf, true); x = x > y ? x : y;
    y = (unsigned)__builtin_amdgcn_update_dpp(0, (int)x, 0x114, 0xf, 0xf, true); x = x > y ? x : y;
    y = (unsigned)__builtin_amdgcn_update_dpp(0, (int)x, 0x118, 0xf, 0xf, true); x = x > y ? x : y;
    y = (unsigned)__builtin_amdgcn_update_dpp(0, (int)x, 0x142, 0xf, 0xf, true); x = x > y ? x : y;
    y = (unsigned)__builtin_amdgcn_update_dpp(0, (int)x, 0x143, 0xf, 0xf, true); x = x > y ? x : y;
    return x;
}

__global__ __launch_bounds__(FPS_T, 4)
void fps_kernel(const float* __restrict__ x, float* __restrict__ out) {
    const int b = blockIdx.x;
    const float* xb = x + (size_t)b * FPS_N * 3;
    float* ob = out + (size_t)b * FPS_M * 3;

    __shared__ char s_pad[96 * 1024];        // 1 block/CU fence (free)
    __shared__ unsigned long long s_vm[FPS_WAVES];   // val<<32 | besti
    __shared__ unsigned long long s_xy[FPS_WAVES];   // xbits<<32 | ybits
    __shared__ unsigned s_z[FPS_WAVES];
    __shared__ unsigned long long s_bc[3];           // coord<<32 | stamp

    const int t = threadIdx.x;
    const int wave = t >> 6;
    const int lane = t & 63;

    ((volatile char*)s_pad)[t * 96] = 0;
    if (t < 3) WG_STORE(&s_bc[t], 0ull);
    __syncthreads();   // one-time init barrier

    // 64 points/thread, register-resident. point i = k*1024 + t.
    v2f X[FPS_NP], Y[FPS_NP], Z[FPS_NP], M[FPS_NP];
#pragma unroll
    for (int j = 0; j < FPS_NP; ++j) {
        const int i0 = (2 * j) * FPS_T + t, i1 = i0 + FPS_T;
        X[j] = (v2f){xb[3 * i0 + 0], xb[3 * i1 + 0]};
        Y[j] = (v2f){xb[3 * i0 + 1], xb[3 * i1 + 1]};
        Z[j] = (v2f){xb[3 * i0 + 2], xb[3 * i1 + 2]};
        M[j] = (v2f){INFINITY, INFINITY};
    }

    float px = xb[0], py = xb[1], pz = xb[2];
    if (t == 0) { ob[0] = px; ob[1] = py; ob[2] = pz; }

    long long budget = 1LL << 22;  // fail-safe for the LDS bcast spin

    for (int s = 1; s < FPS_M; ++s) {
#pragma unroll
        for (int j = 0; j < FPS_NP; j += 4) {
            PIN4(X[j], X[j+1], X[j+2], X[j+3]);
            PIN4(Y[j], Y[j+1], Y[j+2], Y[j+3]);
            PIN4(Z[j], Z[j+1], Z[j+2], Z[j+3]);
        }

        const v2f vnx = (v2f){-px, -px};
        const v2f vny = (v2f){-py, -py};
        const v2f vnz = (v2f){-pz, -pz};

#pragma unroll
        for (int j = 0; j < FPS_NP; ++j) {
            const v2f dx = pk_add(X[j], vnx);
            const v2f dy = pk_add(Y[j], vny);
            const v2f dz = pk_add(Z[j], vnz);
            const v2f sxy = pk_add(pk_mul(dx, dx), pk_mul(dy, dy));
            const v2f dd = pk_fma(dz, dz, sxy);
            M[j].x = fminf(M[j].x, dd.x);
            M[j].y = fminf(M[j].y, dd.y);
        }

        // tournament argmax over 64 local values (ties keep left = lower k)
        float pv_[FPS_NP]; int pe_[FPS_NP];
#pragma unroll
        for (int j = 0; j < FPS_NP; ++j) {
            const bool r = (M[j].y > M[j].x);
            pv_[j] = r ? M[j].y : M[j].x;
            pe_[j] = r ? (2 * j + 1) : (2 * j);
        }
#pragma unroll
        for (int w = FPS_NP / 2; w >= 1; w >>= 1)
#pragma unroll
            for (int j = 0; j < w; ++j) {
                const bool r = (pv_[2 * j + 1] > pv_[2 * j]);
                pv_[j] = r ? pv_[2 * j + 1] : pv_[2 * j];
                pe_[j] = r ? pe_[2 * j + 1] : pe_[2 * j];
            }
        const float best = pv_[0];
        const int besti = (pe_[0] << 10) | t;   // global idx = k*1024 + t

        // wave argmax: DPP umax on val bits, then keyed min-idx
        const unsigned vb = __float_as_uint(best);
        const unsigned mv = (unsigned)__builtin_amdgcn_readlane((int)dppmax(vb), 63);
        const unsigned key = (vb == mv)
            ? ((((unsigned)(~besti) & 0xFFFFu) << 5) | 1u) : 0u;
        const unsigned mk = (unsigned)__builtin_amdgcn_readlane((int)dppmax(key), 63);
        const int wbesti = (int)(~(mk >> 5) & 0xFFFFu);

        // winner coords: kw (0..63) wave-uniform; owner lane = wbesti & 63
        const int kw = wbesti >> 10;
        const int wl = wbesti & 63;
        float sx, sy, sz;
        switch (kw) {
#define CS(K) case K: sx = ((K) & 1) ? X[(K) >> 1].y : X[(K) >> 1].x; \
                      sy = ((K) & 1) ? Y[(K) >> 1].y : Y[(K) >> 1].x; \
                      sz = ((K) & 1) ? Z[(K) >> 1].y : Z[(K) >> 1].x; break;
            CS(0) CS(1) CS(2) CS(3) CS(4) CS(5) CS(6) CS(7)
            CS(8) CS(9) CS(10) CS(11) CS(12) CS(13) CS(14) CS(15)
            CS(16) CS(17) CS(18) CS(19) CS(20) CS(21) CS(22) CS(23)
            CS(24) CS(25) CS(26) CS(27) CS(28) CS(29) CS(30) CS(31)
            CS(32) CS(33) CS(34) CS(35) CS(36) CS(37) CS(38) CS(39)
            CS(40) CS(41) CS(42) CS(43) CS(44) CS(45) CS(46) CS(47)
            CS(48) CS(49) CS(50) CS(51) CS(52) CS(53) CS(54) CS(55)
            CS(56) CS(57) CS(58) CS(59) CS(60) CS(61) CS(62)
            default: sx = X[31].y; sy = Y[31].y; sz = Z[31].y; break;
#undef CS
        }
        const unsigned wxb = (unsigned)__builtin_amdgcn_readlane((int)__float_as_uint(sx), wl);
        const unsigned wyb = (unsigned)__builtin_amdgcn_readlane((int)__float_as_uint(sy), wl);
        const unsigned wzb = (unsigned)__builtin_amdgcn_readlane((int)__float_as_uint(sz), wl);

        // deposit wave winner (lane 0; values wave-uniform)
        if (lane == 0) {
            s_vm[wave] = ((unsigned long long)mv << 32) | (unsigned)wbesti;
            s_xy[wave] = ((unsigned long long)wxb << 32) | wyb;
            s_z[wave]  = wzb;
        }
        __syncthreads();   // bar1: deposits visible; also fences bcast reuse

        const unsigned long long want = (unsigned long long)s;

        if (wave == 0) {
            // combine 16 wave entries via DPP
            const unsigned long long vm = s_vm[lane & 15];
            const unsigned ev = (lane < 16) ? (unsigned)(vm >> 32) : 0u;
            const unsigned em = (unsigned)vm;
            const unsigned mv2 = (unsigned)__builtin_amdgcn_readlane((int)dppmax(ev), 63);
            const unsigned key2 = (lane < 16 && ev == mv2)
                ? ((((~em) & 0xFFFFu) << 5) | (unsigned)(lane + 1)) : 0u;
            const unsigned mk2 = (unsigned)__builtin_amdgcn_readlane((int)dppmax(key2), 63);
            const int wE = (int)(mk2 & 0x1Fu) - 1;   // winning wave
            const unsigned long long cxy = s_xy[wE];
            const unsigned czb = s_z[wE];
            const unsigned xw = (unsigned)(cxy >> 32);
            const unsigned yw = (unsigned)cxy;
            const unsigned zw = czb;

            if (lane == 0) {
                WG_STORE(&s_bc[0], ((unsigned long long)xw << 32) | want);
                WG_STORE(&s_bc[1], ((unsigned long long)yw << 32) | want);
                WG_STORE(&s_bc[2], ((unsigned long long)zw << 32) | want);
                ob[3 * s + 0] = __uint_as_float(xw);
                ob[3 * s + 1] = __uint_as_float(yw);
                ob[3 * s + 2] = __uint_as_float(zw);
            }
            px = __uint_as_float(xw);
            py = __uint_as_float(yw);
            pz = __uint_as_float(zw);
        } else {
            // stamped LDS spin (release point: gates next deposits after
            // wave0's s_vm reads — r13-proven race-free chain)
            unsigned long long b0, b1, b2;
            do { b0 = WG_LOAD(&s_bc[0]); } while ((b0 & 0x7FFull) != want && --budget > 0);
            do { b1 = WG_LOAD(&s_bc[1]); } while ((b1 & 0x7FFull) != want && --budget > 0);
            do { b2 = WG_LOAD(&s_bc[2]); } while ((b2 & 0x7FFull) != want && --budget > 0);
            px = __uint_as_float((unsigned)(b0 >> 32));
            py = __uint_as_float((unsigned)(b1 >> 32));
            pz = __uint_as_float((unsigned)(b2 >> 32));
        }
    }
}

extern "C" void kernel_launch(void* const* d_in, const int* in_sizes, int n_in,
                              void* d_out, int out_size, void* d_ws, size_t ws_size,
                              hipStream_t stream) {
    const float* x = (const float*)d_in[0];
    float* out = (float*)d_out;
    (void)in_sizes; (void)n_in; (void)out_size; (void)d_ws; (void)ws_size;
    fps_kernel<<<FPS_B, FPS_T, 0, stream>>>(x, out);
}

// Round 16
// 5591.921 us; speedup vs baseline: 31.6164x; 31.6164x over previous
//
#include <hip/hip_runtime.h>

// FPS: x (B=64, N=65536, 3) f32 -> out (B, M=2048, 3) f32 gathered points.
// Verified fp semantics (round 3, absmax=0):
//   d = fma(dz,dz, round(dx*dx) + round(dy*dy)), min via fminf,
//   argmax tie-break = smallest global index.
// Round-16 = round-15 with the rowmax16 read-lane bug fixed: row_shr DPP
// produces a PREFIX max whose 16-lane result lands in lane 15 (not 0).
// r15 read lane 0 => block/slot combines returned entry 0 => wrong winner.
// All r15 structure kept: parallel LDS prefetch + readlane(wE) coord
// extract, 4-hop rowmax16 combines, single-word acquire/release broadcast.
// Global ring/slot protocol byte-identical to r10/r13.

#define FPS_B 64
#define FPS_N 65536
#define FPS_M 2048
#define FPS_T 1024
#define FPS_Q 4
#define FPS_GT (FPS_T * FPS_Q)     // 4096 threads per batch
#define FPS_WAVES (FPS_T / 64)

#define SLOT_U64 8
#define BATCH_U64 (FPS_Q * 2 * SLOT_U64)

#define AG_LOAD(p)    __hip_atomic_load((p), __ATOMIC_RELAXED, __HIP_MEMORY_SCOPE_AGENT)
#define AG_STORE(p,v) __hip_atomic_store((p), (v), __ATOMIC_RELAXED, __HIP_MEMORY_SCOPE_AGENT)

typedef float v2f __attribute__((ext_vector_type(2)));

static __device__ __forceinline__ v2f pk_add(v2f a, v2f b) {
    v2f d; asm("v_pk_add_f32 %0, %1, %2" : "=v"(d) : "v"(a), "v"(b)); return d;
}
static __device__ __forceinline__ v2f pk_mul(v2f a, v2f b) {
    v2f d; asm("v_pk_mul_f32 %0, %1, %2" : "=v"(d) : "v"(a), "v"(b)); return d;
}
static __device__ __forceinline__ v2f pk_fma(v2f a, v2f b, v2f c) {
    v2f d; asm("v_pk_fma_f32 %0, %1, %2, %3" : "=v"(d) : "v"(a), "v"(b), "v"(c)); return d;
}

#define PIN4(a,b,c,d) asm volatile("" : "+v"(a), "+v"(b), "+v"(c), "+v"(d))

// 6-step DPP max-reduce over 64 lanes (nonneg u32, identity 0) -> lane 63.
static __device__ __forceinline__ unsigned dppmax(unsigned x) {
    unsigned y;
    y = (unsigned)__builtin_amdgcn_update_dpp(0, (int)x, 0x111, 0xf, 0xf, true); x = x > y ? x : y;
    y = (unsigned)__builtin_amdgcn_update_dpp(0, (int)x, 0x112, 0xf, 0xf, true); x = x > y ? x : y;
    y = (unsigned)__builtin_amdgcn_update_dpp(0, (int)x, 0x114, 0xf, 0xf, true); x = x > y ? x : y;
    y = (unsigned)__builtin_amdgcn_update_dpp(0, (int)x, 0x118, 0xf, 0xf, true); x = x > y ? x : y;
    y = (unsigned)__builtin_amdgcn_update_dpp(0, (int)x, 0x142, 0xf, 0xf, true); x = x > y ? x : y;
    y = (unsigned)__builtin_amdgcn_update_dpp(0, (int)x, 0x143, 0xf, 0xf, true); x = x > y ? x : y;
    return x;
}

// 4-step row_shr max-reduce over lanes 0..15 (nonneg u32) -> result LANE 15.
static __device__ __forceinline__ unsigned rowmax16(unsigned x) {
    unsigned y;
    y = (unsigned)__builtin_amdgcn_update_dpp(0, (int)x, 0x111, 0xf, 0xf, true); x = x > y ? x : y;
    y = (unsigned)__builtin_amdgcn_update_dpp(0, (int)x, 0x112, 0xf, 0xf, true); x = x > y ? x : y;
    y = (unsigned)__builtin_amdgcn_update_dpp(0, (int)x, 0x114, 0xf, 0xf, true); x = x > y ? x : y;
    y = (unsigned)__builtin_amdgcn_update_dpp(0, (int)x, 0x118, 0xf, 0xf, true); x = x > y ? x : y;
    return x;
}

__global__ __launch_bounds__(FPS_T, 4)
void fps_kernel(const float* __restrict__ x, float* __restrict__ out,
                unsigned long long* __restrict__ cand) {
    const int bid = blockIdx.x;
    const int c = bid & 7;
    const int v = bid >> 3;
    const int q = v & 3;
    const int b = (v >> 2) * 8 + c;

    const float* xb = x + (size_t)b * FPS_N * 3;
    float* ob = out + (size_t)b * FPS_M * 3;
    unsigned long long* cb = cand + (size_t)b * BATCH_U64;

    __shared__ char s_pad[96 * 1024];        // 1 block/CU fence
    __shared__ unsigned long long s_vm[FPS_WAVES];   // val<<32 | besti
    __shared__ unsigned long long s_xy[FPS_WAVES];   // xbits<<32 | ybits
    __shared__ unsigned s_z[FPS_WAVES];
    __shared__ unsigned s_bcw[4];                    // {x,y,z,stamp}

    const int t = threadIdx.x;
    const int wave = t >> 6;
    const int lane = t & 63;
    const int g = q * FPS_T + t;

    ((volatile char*)s_pad)[t * 96] = 0;
    if (t < 4) s_bcw[t] = 0u;
    __syncthreads();   // one-time init barrier

    v2f X0,X1,X2,X3,X4,X5,X6,X7;
    v2f Y0,Y1,Y2,Y3,Y4,Y5,Y6,Y7;
    v2f Z0,Z1,Z2,Z3,Z4,Z5,Z6,Z7;
    v2f M0,M1,M2,M3,M4,M5,M6,M7;
#define LOADP(j) do { \
        const int i0 = (2*(j)) * FPS_GT + g, i1 = i0 + FPS_GT; \
        X##j = (v2f){xb[3*i0+0], xb[3*i1+0]}; \
        Y##j = (v2f){xb[3*i0+1], xb[3*i1+1]}; \
        Z##j = (v2f){xb[3*i0+2], xb[3*i1+2]}; \
        M##j = (v2f){INFINITY, INFINITY}; } while (0)
    LOADP(0); LOADP(1); LOADP(2); LOADP(3);
    LOADP(4); LOADP(5); LOADP(6); LOADP(7);
#undef LOADP

    float px = xb[0], py = xb[1], pz = xb[2];
    if (q == 0 && t == 0) { ob[0] = px; ob[1] = py; ob[2] = pz; }

    long long budget = 1LL << 22;

    for (int s = 1; s < FPS_M; ++s) {
        PIN4(X0,X1,X2,X3); PIN4(X4,X5,X6,X7);
        PIN4(Y0,Y1,Y2,Y3); PIN4(Y4,Y5,Y6,Y7);
        PIN4(Z0,Z1,Z2,Z3); PIN4(Z4,Z5,Z6,Z7);

        const v2f vnx = (v2f){-px, -px};
        const v2f vny = (v2f){-py, -py};
        const v2f vnz = (v2f){-pz, -pz};

#define STEPP(j) do { \
        const v2f dx = pk_add(X##j, vnx); \
        const v2f dy = pk_add(Y##j, vny); \
        const v2f dz = pk_add(Z##j, vnz); \
        const v2f sxy = pk_add(pk_mul(dx, dx), pk_mul(dy, dy)); \
        const v2f dd = pk_fma(dz, dz, sxy); \
        M##j.x = fminf(M##j.x, dd.x); \
        M##j.y = fminf(M##j.y, dd.y); } while (0)
        STEPP(0); STEPP(1); STEPP(2); STEPP(3);
        STEPP(4); STEPP(5); STEPP(6); STEPP(7);
#undef STEPP

        // tournament argmax over the 16 md values (ties keep left = first k)
#define PAIR(j) float p##j = (M##j.y > M##j.x) ? M##j.y : M##j.x; \
                int   e##j = (M##j.y > M##j.x) ? (2*(j)+1) : (2*(j))
        PAIR(0); PAIR(1); PAIR(2); PAIR(3);
        PAIR(4); PAIR(5); PAIR(6); PAIR(7);
#undef PAIR
        float a0 = (p1 > p0) ? p1 : p0;  int c0 = (p1 > p0) ? e1 : e0;
        float a1 = (p3 > p2) ? p3 : p2;  int c1 = (p3 > p2) ? e3 : e2;
        float a2 = (p5 > p4) ? p5 : p4;  int c2 = (p5 > p4) ? e5 : e4;
        float a3 = (p7 > p6) ? p7 : p6;  int c3 = (p7 > p6) ? e7 : e6;
        float d0 = (a1 > a0) ? a1 : a0;  int f0 = (a1 > a0) ? c1 : c0;
        float d1 = (a3 > a2) ? a3 : a2;  int f1 = (a3 > a2) ? c3 : c2;
        float best = (d1 > d0) ? d1 : d0;
        int bk = (d1 > d0) ? f1 : f0;
        const int besti = (bk << 12) | g;

        // wave argmax: DPP umax on val bits, then keyed min-idx (proven r13)
        const unsigned vb = __float_as_uint(best);
        const unsigned mv = (unsigned)__builtin_amdgcn_readlane((int)dppmax(vb), 63);
        const unsigned key = (vb == mv)
            ? ((((unsigned)(~besti) & 0xFFFFu) << 5) | 1u) : 0u;
        const unsigned mk = (unsigned)__builtin_amdgcn_readlane((int)dppmax(key), 63);
        const int wbesti = (int)(~(mk >> 5) & 0xFFFFu);

        const int kw = wbesti >> 12;
        const int wl = wbesti & 63;
        float sx, sy, sz;
        switch (kw) {
            case  0: sx = X0.x; sy = Y0.x; sz = Z0.x; break;
            case  1: sx = X0.y; sy = Y0.y; sz = Z0.y; break;
            case  2: sx = X1.x; sy = Y1.x; sz = Z1.x; break;
            case  3: sx = X1.y; sy = Y1.y; sz = Z1.y; break;
            case  4: sx = X2.x; sy = Y2.x; sz = Z2.x; break;
            case  5: sx = X2.y; sy = Y2.y; sz = Z2.y; break;
            case  6: sx = X3.x; sy = Y3.x; sz = Z3.x; break;
            case  7: sx = X3.y; sy = Y3.y; sz = Z3.y; break;
            case  8: sx = X4.x; sy = Y4.x; sz = Z4.x; break;
            case  9: sx = X4.y; sy = Y4.y; sz = Z4.y; break;
            case 10: sx = X5.x; sy = Y5.x; sz = Z5.x; break;
            case 11: sx = X5.y; sy = Y5.y; sz = Z5.y; break;
            case 12: sx = X6.x; sy = Y6.x; sz = Z6.x; break;
            case 13: sx = X6.y; sy = Y6.y; sz = Z6.y; break;
            case 14: sx = X7.x; sy = Y7.x; sz = Z7.x; break;
            default: sx = X7.y; sy = Y7.y; sz = Z7.y; break;
        }
        const unsigned wxb = (unsigned)__builtin_amdgcn_readlane((int)__float_as_uint(sx), wl);
        const unsigned wyb = (unsigned)__builtin_amdgcn_readlane((int)__float_as_uint(sy), wl);
        const unsigned wzb = (unsigned)__builtin_amdgcn_readlane((int)__float_as_uint(sz), wl);

        if (lane == 0) {
            s_vm[wave] = ((unsigned long long)mv << 32) | (unsigned)wbesti;
            s_xy[wave] = ((unsigned long long)wxb << 32) | wyb;
            s_z[wave]  = wzb;
        }
        __syncthreads();   // bar1

        const unsigned long long want = (unsigned long long)s;
        const int ring = s & 1;

        if (wave == 0) {
            // parallel prefetch of all three entry arrays (independent loads)
            const unsigned long long vm = s_vm[lane & 15];
            const unsigned long long xyL = s_xy[lane & 15];
            const unsigned zL = s_z[lane & 15];
            const unsigned xHi = (unsigned)(xyL >> 32);
            const unsigned xLo = (unsigned)xyL;

            const unsigned ev = (lane < 16) ? (unsigned)(vm >> 32) : 0u;
            const unsigned em = (unsigned)vm;
            const unsigned mv2 = (unsigned)__builtin_amdgcn_readlane((int)rowmax16(ev), 15);
            const unsigned key2 = (lane < 16 && ev == mv2)
                ? ((((~em) & 0xFFFFu) << 5) | (unsigned)(lane + 1)) : 0u;
            const unsigned mk2 = (unsigned)__builtin_amdgcn_readlane((int)rowmax16(key2), 15);
            const int wE = (int)(mk2 & 0x1Fu) - 1;
            const unsigned nidx = (mk2 >> 5) & 0xFFFFu;
            // coord extract from prefetched lanes (no dependent LDS load)
            const unsigned exw = (unsigned)__builtin_amdgcn_readlane((int)xHi, wE);
            const unsigned eyw = (unsigned)__builtin_amdgcn_readlane((int)xLo, wE);
            const unsigned ezw = (unsigned)__builtin_amdgcn_readlane((int)zL, wE);

            // publish block winner (lanes 0-3, slot format == r10/r13)
            if (lane < 4) {
                unsigned long long w;
                if (lane == 0)
                    w = (((unsigned long long)mv2) << 32) |
                        (((unsigned long long)nidx) << 11) | want;
                else if (lane == 1) w = ((unsigned long long)exw << 32) | want;
                else if (lane == 2) w = ((unsigned long long)eyw << 32) | want;
                else                w = ((unsigned long long)ezw << 32) | want;
                AG_STORE(&cb[(q * 2 + ring) * SLOT_U64 + lane], w);
            }
            // merged poll: lane -> word (lane&15)&3 of slot (lane&15)>>2
            const int gl = lane & 15;
            unsigned long long pv = 0;
            bool ok = false;
            do {
                if (!ok) {
                    pv = AG_LOAD(&cb[((gl >> 2) * 2 + ring) * SLOT_U64 + (gl & 3)]);
                    ok = ((pv & 0x7FFull) == want);
                }
            } while (!__all(ok) && --budget > 0);

            // combine 4 slot word0s via rowmax16 (result lane 15)
            const unsigned hi = (unsigned)(pv >> 32);
            const bool w0lane = ((lane & 3) == 0) && (lane < 16);
            const unsigned pvv = w0lane ? hi : 0u;
            const unsigned mv3 = (unsigned)__builtin_amdgcn_readlane((int)rowmax16(pvv), 15);
            const unsigned key3 = (w0lane && pvv == mv3)
                ? (((((unsigned)(pv >> 11)) & 0xFFFFu) << 7) | (unsigned)((lane >> 2) + 1)) : 0u;
            const unsigned mk3 = (unsigned)__builtin_amdgcn_readlane((int)rowmax16(key3), 15);
            const int wb = (int)(mk3 & 0x7Fu) - 1;
            const unsigned xw = (unsigned)__builtin_amdgcn_readlane((int)hi, wb * 4 + 1);
            const unsigned yw = (unsigned)__builtin_amdgcn_readlane((int)hi, wb * 4 + 2);
            const unsigned zw = (unsigned)__builtin_amdgcn_readlane((int)hi, wb * 4 + 3);

            if (lane == 0) {
                s_bcw[0] = xw; s_bcw[1] = yw; s_bcw[2] = zw;
                __hip_atomic_store(&s_bcw[3], (unsigned)s,
                                   __ATOMIC_RELEASE, __HIP_MEMORY_SCOPE_WORKGROUP);
                if (q == 0) {
                    ob[3 * s + 0] = __uint_as_float(xw);
                    ob[3 * s + 1] = __uint_as_float(yw);
                    ob[3 * s + 2] = __uint_as_float(zw);
                }
            }
            px = __uint_as_float(xw);
            py = __uint_as_float(yw);
            pz = __uint_as_float(zw);
        } else {
            // single-word acquire spin, then payload reads (ordered by acq)
            unsigned st;
            do {
                st = __hip_atomic_load(&s_bcw[3], __ATOMIC_ACQUIRE,
                                       __HIP_MEMORY_SCOPE_WORKGROUP);
            } while (st != (unsigned)s && --budget > 0);
            px = __uint_as_float(s_bcw[0]);
            py = __uint_as_float(s_bcw[1]);
            pz = __uint_as_float(s_bcw[2]);
        }
    }
}

extern "C" void kernel_launch(void* const* d_in, const int* in_sizes, int n_in,
                              void* d_out, int out_size, void* d_ws, size_t ws_size,
                              hipStream_t stream) {
    const float* x = (const float*)d_in[0];
    float* out = (float*)d_out;
    unsigned long long* cand = (unsigned long long*)d_ws;
    (void)in_sizes; (void)n_in; (void)out_size; (void)ws_size;
    hipMemsetAsync(d_ws, 0, FPS_B * BATCH_U64 * sizeof(unsigned long long), stream);
    fps_kernel<<<FPS_B * FPS_Q, FPS_T, 0, stream>>>(x, out, cand);
}